// Round 1
// 616.227 us; speedup vs baseline: 1.0164x; 1.0164x over previous
//
#include <hip/hip_runtime.h>

// Problem: B=8, Lq=Lk=2048, D=640, fp32.
//   logits = (2*q.k - ||q||^2 - ||k||^2) / 13
//   log_attn = log_softmax(logits); attn = exp(log_attn); out = attn @ v
// Outputs concatenated in d_out: out (8*2048*640) | attn (8*2048*2048) | log_attn (8*2048*2048)

#define B_   8
#define LQ   2048
#define LK   2048
#define DD   640

typedef short s16x8 __attribute__((ext_vector_type(8)));
typedef float f32x4 __attribute__((ext_vector_type(4)));

__device__ __forceinline__ unsigned short f2bf(float x) {
    unsigned int u = __float_as_uint(x);
    unsigned int r = (u + 0x7fffu + ((u >> 16) & 1u)) >> 16;
    return (unsigned short)r;
}

// ---------------------------------------------------------------------------
// K0a: fp32 -> bf16 convert + row sum-of-squares for BOTH q and k in one
// launch. One wave per row (D=640). grid = 2*B*L/4, block = 256.
__global__ __launch_bounds__(256) void cvt_norm2(const float* __restrict__ q,
                                                 const float* __restrict__ k,
                                                 unsigned short* __restrict__ q16,
                                                 unsigned short* __restrict__ k16,
                                                 float* __restrict__ qq,
                                                 float* __restrict__ kkn) {
    int row  = blockIdx.x * 4 + (threadIdx.x >> 6);
    int lane = threadIdx.x & 63;
    const float* src;
    unsigned short* dst;
    float* nrm;
    int r;
    if (row < B_ * LQ) { src = q; dst = q16; nrm = qq;  r = row; }
    else               { src = k; dst = k16; nrm = kkn; r = row - B_ * LQ; }
    const float4* s = (const float4*)(src + (size_t)r * DD);
    unsigned short* d = dst + (size_t)r * DD;
    float ss = 0.f;
    for (int t = lane; t < DD / 4; t += 64) {
        float4 x = s[t];
        ss += x.x * x.x + x.y * x.y + x.z * x.z + x.w * x.w;
        ushort4 o;
        o.x = f2bf(x.x); o.y = f2bf(x.y); o.z = f2bf(x.z); o.w = f2bf(x.w);
        *(ushort4*)(d + t * 4) = o;
    }
    #pragma unroll
    for (int o = 32; o; o >>= 1) ss += __shfl_xor(ss, o);
    if (lane == 0) nrm[r] = ss;
}

// ---------------------------------------------------------------------------
// K0b: v (B, 2048, 640) fp32 -> v^T (B, 640, 2048) bf16, 64x64 LDS tiles.
// grid = B * 32 * 10, block = 256.
__global__ __launch_bounds__(256) void cvt_transpose_v(const float* __restrict__ v,
                                                       unsigned short* __restrict__ vt) {
    __shared__ float tile[64][65];
    int bx = blockIdx.x;
    int b  = bx / 320;
    int r  = bx % 320;
    int tj = r / 10;   // j-tile (0..31)
    int td = r % 10;   // d-tile (0..9)
    const float* src = v + (size_t)b * LK * DD + (size_t)tj * 64 * DD + td * 64;
    for (int e = threadIdx.x; e < 4096; e += 256) {
        int rr = e >> 6, cc = e & 63;
        tile[rr][cc] = src[(size_t)rr * DD + cc];
    }
    __syncthreads();
    unsigned short* dst = vt + (size_t)b * DD * LK + (size_t)td * 64 * LK + tj * 64;
    for (int e = threadIdx.x; e < 4096; e += 256) {
        int rr = e >> 6, cc = e & 63;  // rr = local d, cc = local j
        dst[(size_t)rr * LK + cc] = f2bf(tile[cc][rr]);
    }
}

// ---------------------------------------------------------------------------
// NT-GEMM, 256-wide 8-wave counted-vmcnt structure (T2+T4+T5):
//   C[i][j] = sum_d A[i][d] * B[j][d], A/B bf16 row-major.
// BM=256, BN=256 (QK^T) or 128 (PV), BK=64, 512 threads = 8 waves (WMxWN).
// LDS per operand per buffer: K-half-split [2][rows][32] bf16 (64-B rows) with
// XOR chunk swizzle ch ^= (row>>1)&3 -> conflict-free ds_read_b128
// (lanes 0..7 hit bank quads {0,16,4,20,8,24,12,28}; verified by enumeration).
// global_load_lds: LINEAR LDS dest + pre-swizzled GLOBAL source (rule #21).
// Schedule per K-tile t (buffer p = t&1):
//   s_waitcnt vmcnt(L)   // own prefetch of tile t landed; t+1 still in flight
//   s_barrier            // all waves' slices of tile t visible
//   [cache B frags; 2 phases: load A-half frags, setprio(1), 32 MFMA, setprio(0)]
//   sched_barrier(0); s_barrier    // all waves done reading buffer p
//   stage(tile t+2 -> p) // issue-after-free: no write/read race by construction
// Loads are never drained to 0 inside the loop (the m97 ~20% stall).
// Tail prefetch clamps to tile 0 (valid addrs, dead data) to keep vmcnt uniform.
// XCD swizzle: tm = blockIdx.x & 7 (M-tiles per batch == 8 == XCDs) so each
// XCD's L2 holds one A strip per batch.
// EPI=true: val = (2*acc - qq[row] - kk[col]) / 13  (QK^T logits epilogue).
template <int LDA, int LDB, int KSZ, int NTN, int BN, int WM, int WN, bool EPI>
__global__ __launch_bounds__(512, 2) void gemm_nt256(
    const unsigned short* __restrict__ A, const unsigned short* __restrict__ Bm,
    float* __restrict__ C, size_t strideA, size_t strideB, size_t strideC, int ldc,
    const float* __restrict__ qq, const float* __restrict__ kkn) {

    constexpr int KT   = KSZ / 64;        // K-tiles
    constexpr int RM   = 256 / WM / 16;   // m16 frags per wave
    constexpr int RN   = BN  / WN / 16;   // n16 frags per wave
    constexpr int LBLD = BN / 64;         // B stage loads per thread (A is 4)

    __shared__ unsigned short lA[2 * 2 * 256 * 32];   // 64 KB (dbuf x khalf x 256 x 32)
    __shared__ unsigned short lB[2 * 2 * BN  * 32];   // 64 or 32 KB

    int bx = blockIdx.x;
    int tm = bx & 7;            // M-tile == XCD id (8 M-tiles per batch)
    int i  = bx >> 3;
    int tn = i % NTN;
    int b  = i / NTN;

    const unsigned short* Ab = A  + b * strideA + (size_t)tm * 256 * LDA;
    const unsigned short* Bb = Bm + b * strideB + (size_t)tn * BN  * LDB;

    int tid  = threadIdx.x;
    int w    = tid >> 6;
    int lane = tid & 63;
    int lrow = lane & 15;
    int lk4  = lane >> 4;       // logical 16B chunk within 64B K-half row
    int wm   = w / WN;
    int wn   = w % WN;

    // Stage one K-tile (A: 4 loads/thread, B: LBLD loads/thread), linear LDS
    // dest (wave-uniform base + lane*16B), pre-swizzled global source.
    auto stage = [&](int kt, int p) {
        int k0 = kt * 64;
        #pragma unroll
        for (int s = 0; s < 4; ++s) {
            int row = ((s & 1) << 7) | (tid >> 2);
            int kh  = s >> 1;
            int ch  = tid & 3;
            int sc  = k0 + kh * 32 + ((ch ^ ((row >> 1) & 3)) << 3);
            __builtin_amdgcn_global_load_lds(
                (const __attribute__((address_space(1))) void*)(Ab + (size_t)row * LDA + sc),
                (__attribute__((address_space(3))) void*)(lA + p * 16384 + s * 4096 + w * 512),
                16, 0, 0);
        }
        #pragma unroll
        for (int s = 0; s < LBLD; ++s) {
            int o  = s * 8192 + tid * 16;          // byte offset in B p-buffer
            int kh = o / (BN * 64);
            int rr = (o & (BN * 64 - 1)) >> 6;
            int ch = (o >> 4) & 3;
            int sc = k0 + kh * 32 + ((ch ^ ((rr >> 1) & 3)) << 3);
            __builtin_amdgcn_global_load_lds(
                (const __attribute__((address_space(1))) void*)(Bb + (size_t)rr * LDB + sc),
                (__attribute__((address_space(3))) void*)(lB + p * (BN * 64) + s * 4096 + w * 512),
                16, 0, 0);
        }
    };

    f32x4 acc[RM][RN] = {};

    stage(0, 0);
    stage(1, 1);

    #pragma unroll 2
    for (int t = 0; t < KT; ++t) {
        int p = t & 1;
        // Wait for OWN tile-t loads only (oldest L of 2L in flight); barrier
        // then makes every wave's slice visible. Never vmcnt(0) in-loop.
        if constexpr (BN == 256) asm volatile("s_waitcnt vmcnt(8)" ::: "memory");
        else                     asm volatile("s_waitcnt vmcnt(6)" ::: "memory");
        __builtin_amdgcn_s_barrier();
        __builtin_amdgcn_sched_barrier(0);
        asm volatile("" ::: "memory");

        const unsigned short* pA = lA + p * 16384;
        const unsigned short* pB = lB + p * (BN * 64);

        // Cache the wave's B fragments for the whole tile (RN*2 frags).
        s16x8 bf[RN][2];
        #pragma unroll
        for (int n = 0; n < RN; ++n)
            #pragma unroll
            for (int kh = 0; kh < 2; ++kh) {
                int br = wn * (RN * 16) + n * 16 + lrow;
                bf[n][kh] = *(const s16x8*)(pB + kh * (BN * 32) + br * 32 +
                                            ((lk4 ^ ((br >> 1) & 3)) << 3));
            }

        // Two phases over the wave's M range; A frags re-loaded per phase.
        #pragma unroll
        for (int qm = 0; qm < 2; ++qm) {
            s16x8 af[RM / 2][2];
            #pragma unroll
            for (int m = 0; m < RM / 2; ++m)
                #pragma unroll
                for (int kh = 0; kh < 2; ++kh) {
                    int ar = wm * (RM * 16) + (qm * (RM / 2) + m) * 16 + lrow;
                    af[m][kh] = *(const s16x8*)(pA + kh * 8192 + ar * 32 +
                                                ((lk4 ^ ((ar >> 1) & 3)) << 3));
                }
            __builtin_amdgcn_s_setprio(1);
            #pragma unroll
            for (int kh = 0; kh < 2; ++kh)
                #pragma unroll
                for (int m = 0; m < RM / 2; ++m)
                    #pragma unroll
                    for (int n = 0; n < RN; ++n)
                        acc[qm * (RM / 2) + m][n] = __builtin_amdgcn_mfma_f32_16x16x32_bf16(
                            af[m][kh], bf[n][kh], acc[qm * (RM / 2) + m][n], 0, 0, 0);
            __builtin_amdgcn_s_setprio(0);
        }

        asm volatile("" ::: "memory");
        __builtin_amdgcn_sched_barrier(0);
        __builtin_amdgcn_s_barrier();        // all waves done reading buffer p
        int t2 = (t + 2 < KT) ? t + 2 : 0;   // clamp tail: valid addrs, dead data
        stage(t2, p);                        // issue-after-free prefetch
    }
    asm volatile("s_waitcnt vmcnt(0)" ::: "memory");

    // Epilogue. C/D layout (m89): col = lane&15, row = (lane>>4)*4 + rr.
    float* Cb = C + b * strideC + (size_t)(tm * 256) * ldc + tn * BN;
    #pragma unroll
    for (int mi = 0; mi < RM; ++mi) {
        int rb = wm * (RM * 16) + mi * 16 + lk4 * 4;
        #pragma unroll
        for (int ni = 0; ni < RN; ++ni) {
            int col = wn * (RN * 16) + ni * 16 + lrow;
            #pragma unroll
            for (int rr = 0; rr < 4; ++rr) {
                float val = acc[mi][ni][rr];
                if constexpr (EPI)
                    val = (2.0f * val - qq[b * LQ + tm * 256 + rb + rr]
                                      - kkn[b * LK + tn * BN + col]) * (1.0f / 13.0f);
                Cb[(size_t)(rb + rr) * ldc + col] = val;
            }
        }
    }
}

// ---------------------------------------------------------------------------
// K2: per-row softmax fixup. One block per (b, q-row); 2048 logits live in
// registers (8/thread). Writes attn fp32, attn bf16 (ws), log_attn (in-place).
__global__ __launch_bounds__(256) void softmax_fix(float* __restrict__ logits,
                                                   float* __restrict__ attn,
                                                   unsigned short* __restrict__ a16) {
    __shared__ float redm[4], reds[4];
    size_t row = blockIdx.x;
    float* Lr = logits + row * LK;
    int tid = threadIdx.x;
    float x[8];
    *(float4*)(x)     = *(const float4*)(Lr + tid * 8);
    *(float4*)(x + 4) = *(const float4*)(Lr + tid * 8 + 4);

    float m = x[0];
    #pragma unroll
    for (int i = 1; i < 8; ++i) m = fmaxf(m, x[i]);
    #pragma unroll
    for (int o = 32; o; o >>= 1) m = fmaxf(m, __shfl_xor(m, o));
    int wv = tid >> 6, ln = tid & 63;
    if (ln == 0) redm[wv] = m;
    __syncthreads();
    m = fmaxf(fmaxf(redm[0], redm[1]), fmaxf(redm[2], redm[3]));

    float e[8];
    float s = 0.f;
    #pragma unroll
    for (int i = 0; i < 8; ++i) { e[i] = __expf(x[i] - m); s += e[i]; }
    #pragma unroll
    for (int o = 32; o; o >>= 1) s += __shfl_xor(s, o);
    if (ln == 0) reds[wv] = s;
    __syncthreads();
    s = reds[0] + reds[1] + reds[2] + reds[3];

    float lse = __logf(s);
    float inv = 1.0f / s;
    float at[8], la[8];
    #pragma unroll
    for (int i = 0; i < 8; ++i) { at[i] = e[i] * inv; la[i] = x[i] - m - lse; }

    float* Ar = attn + row * LK;
    *(float4*)(Ar + tid * 8)     = *(float4*)at;
    *(float4*)(Ar + tid * 8 + 4) = *(float4*)(at + 4);
    *(float4*)(Lr + tid * 8)     = *(float4*)la;
    *(float4*)(Lr + tid * 8 + 4) = *(float4*)(la + 4);

    unsigned short h[8];
    #pragma unroll
    for (int i = 0; i < 8; ++i) h[i] = f2bf(at[i]);
    unsigned short* Hr = a16 + row * LK;
    *(ushort4*)(Hr + tid * 8)     = *(ushort4*)h;
    *(ushort4*)(Hr + tid * 8 + 4) = *(ushort4*)(h + 4);
}

// ---------------------------------------------------------------------------
extern "C" void kernel_launch(void* const* d_in, const int* in_sizes, int n_in,
                              void* d_out, int out_size, void* d_ws, size_t ws_size,
                              hipStream_t stream) {
    const float* q = (const float*)d_in[0];
    const float* k = (const float*)d_in[1];
    const float* v = (const float*)d_in[2];

    float* out   = (float*)d_out;                      // (8, 2048, 640)
    float* attn  = out + (size_t)B_ * LQ * DD;         // (8, 2048, 2048)
    float* logat = attn + (size_t)B_ * LQ * LK;        // (8, 2048, 2048)

    // ws layout (needs ~130.2 MB):
    unsigned short* q16  = (unsigned short*)d_ws;                 // 10485760 bf16
    unsigned short* k16  = q16 + (size_t)B_ * LQ * DD;            // 10485760
    unsigned short* v16t = k16 + (size_t)B_ * LK * DD;            // 10485760 (B, D, LK)
    unsigned short* a16  = v16t + (size_t)B_ * DD * LK;           // 33554432 (B, LQ, LK)
    float* qq  = (float*)(a16 + (size_t)B_ * LQ * LK);            // 16384
    float* kkn = qq + (size_t)B_ * LQ;                            // 16384

    cvt_norm2<<<2 * B_ * LQ / 4, 256, 0, stream>>>(q, k, q16, k16, qq, kkn);
    cvt_transpose_v<<<B_ * (LK / 64) * (DD / 64), 256, 0, stream>>>(v, v16t);

    // QK^T -> raw logits into log_attn region. 256x256 tiles: grid = 8*8*8.
    gemm_nt256<DD, DD, DD, 8, 256, 2, 4, true><<<B_ * 8 * 8, 512, 0, stream>>>(
        q16, k16, logat,
        (size_t)LQ * DD, (size_t)LK * DD, (size_t)LQ * LK, LK, qq, kkn);

    // softmax fixup: one block per row.
    softmax_fix<<<B_ * LQ, 256, 0, stream>>>(logat, attn, a16);

    // PV: attn_bf16 (2048x2048) @ v^T_bf16 (640x2048) -> out.
    // 256x128 tiles, waves 4x2: grid = 8*8*5.
    gemm_nt256<LK, LK, LK, 5, 128, 4, 2, false><<<B_ * 8 * 5, 512, 0, stream>>>(
        a16, v16t, out,
        (size_t)LQ * LK, (size_t)DD * LK, (size_t)LQ * DD, DD, nullptr, nullptr);
}

// Round 2
// 611.041 us; speedup vs baseline: 1.0250x; 1.0085x over previous
//
#include <hip/hip_runtime.h>

// Problem: B=8, Lq=Lk=2048, D=640, fp32.
//   logits = (2*q.k - ||q||^2 - ||k||^2) / 13
//   log_attn = log_softmax(logits); attn = exp(log_attn); out = attn @ v
// Outputs concatenated in d_out: out (8*2048*640) | attn (8*2048*2048) | log_attn (8*2048*2048)

#define B_   8
#define LQ   2048
#define LK   2048
#define DD   640

typedef short s16x8 __attribute__((ext_vector_type(8)));
typedef float f32x4 __attribute__((ext_vector_type(4)));

__device__ __forceinline__ unsigned short f2bf(float x) {
    unsigned int u = __float_as_uint(x);
    unsigned int r = (u + 0x7fffu + ((u >> 16) & 1u)) >> 16;
    return (unsigned short)r;
}

// ---------------------------------------------------------------------------
// K0a: fp32 -> bf16 convert + row sum-of-squares for BOTH q and k in one
// launch. One wave per row (D=640). grid = 2*B*L/4, block = 256.
__global__ __launch_bounds__(256) void cvt_norm2(const float* __restrict__ q,
                                                 const float* __restrict__ k,
                                                 unsigned short* __restrict__ q16,
                                                 unsigned short* __restrict__ k16,
                                                 float* __restrict__ qq,
                                                 float* __restrict__ kkn) {
    int row  = blockIdx.x * 4 + (threadIdx.x >> 6);
    int lane = threadIdx.x & 63;
    const float* src;
    unsigned short* dst;
    float* nrm;
    int r;
    if (row < B_ * LQ) { src = q; dst = q16; nrm = qq;  r = row; }
    else               { src = k; dst = k16; nrm = kkn; r = row - B_ * LQ; }
    const float4* s = (const float4*)(src + (size_t)r * DD);
    unsigned short* d = dst + (size_t)r * DD;
    float ss = 0.f;
    for (int t = lane; t < DD / 4; t += 64) {
        float4 x = s[t];
        ss += x.x * x.x + x.y * x.y + x.z * x.z + x.w * x.w;
        ushort4 o;
        o.x = f2bf(x.x); o.y = f2bf(x.y); o.z = f2bf(x.z); o.w = f2bf(x.w);
        *(ushort4*)(d + t * 4) = o;
    }
    #pragma unroll
    for (int o = 32; o; o >>= 1) ss += __shfl_xor(ss, o);
    if (lane == 0) nrm[r] = ss;
}

// ---------------------------------------------------------------------------
// K0b: v (B, 2048, 640) fp32 -> v^T (B, 640, 2048) bf16, 64x64 LDS tiles.
// grid = B * 32 * 10, block = 256.
__global__ __launch_bounds__(256) void cvt_transpose_v(const float* __restrict__ v,
                                                       unsigned short* __restrict__ vt) {
    __shared__ float tile[64][65];
    int bx = blockIdx.x;
    int b  = bx / 320;
    int r  = bx % 320;
    int tj = r / 10;   // j-tile (0..31)
    int td = r % 10;   // d-tile (0..9)
    const float* src = v + (size_t)b * LK * DD + (size_t)tj * 64 * DD + td * 64;
    for (int e = threadIdx.x; e < 4096; e += 256) {
        int rr = e >> 6, cc = e & 63;
        tile[rr][cc] = src[(size_t)rr * DD + cc];
    }
    __syncthreads();
    unsigned short* dst = vt + (size_t)b * DD * LK + (size_t)td * 64 * LK + tj * 64;
    for (int e = threadIdx.x; e < 4096; e += 256) {
        int rr = e >> 6, cc = e & 63;  // rr = local d, cc = local j
        dst[(size_t)rr * LK + cc] = f2bf(tile[cc][rr]);
    }
}

// ---------------------------------------------------------------------------
// NT-GEMM, 8-wave 256x256 tile, TRUE 4-phase-per-K-tile schedule (T2+T3+T4+T5):
//   C[i][j] = sum_d A[i][d] * B[j][d], A/B bf16 row-major.
// BM=BN=256, BK=64, 512 threads = 8 waves (2M x 4N), per-wave 128x64 output
// (acc[8][4] f32x4 = 128 VGPR). LDS: 2 dbuf x (A 32KB + B 32KB) = 128 KB.
// LDS element layout per op-buffer: [kh][row][chunk^swz] with 64-B rows;
// swizzle ch ^= (row>>1)&3 + row-parity spread -> each 16B slot gets exactly
// 8 of 64 lanes (the b128 minimum) on fragment reads. Staged with LINEAR LDS
// dest + pre-swizzled GLOBAL source (rule #21); read applies same XOR.
// Per K-tile t (buffer p=t&1), 4 phases; phase j:
//   ds_read frags (ph0: 8 B + 4 A; ph1-3: 4 A)
//   ph1/ph2: issue B(t+2) half-chunks into buf p  (B freed after ph0 barrier)
//   sched_barrier+fence; s_barrier; setprio(1); 16 MFMA; setprio(0); barrier
// Iteration end: issue A(t+2) (A freed after ph3 barrier). Tile-ready wait =
// s_waitcnt vmcnt(8) (exactly one tile outstanding) -- never 0 in-loop.
// Last iteration peeled: vmcnt(0), no staging (avoids dead-prefetch races).
// XCD swizzle: tm = blockIdx.x & 7 ties M-strip to XCD for A L2 reuse.
// BCOLS < 256*NTN (PV: 640): B global rows clamped (garbage column-isolated),
// stores guarded by col < bmax. EPI: val = (2*acc - qq[row] - kk[col]) / 13.
template <int LDA, int LDB, int KSZ, int NTN, int BCOLS, bool EPI>
__global__ __launch_bounds__(512, 2) void gemm8p(
    const unsigned short* __restrict__ A, const unsigned short* __restrict__ Bm,
    float* __restrict__ C, size_t strideA, size_t strideB, size_t strideC, int ldc,
    const float* __restrict__ qq, const float* __restrict__ kkn) {

    constexpr int KT = KSZ / 64;

    __shared__ unsigned short lA[2 * 16384];
    __shared__ unsigned short lB[2 * 16384];
    __shared__ float snm[512];

    int bx = blockIdx.x;
    int tm = bx & 7;            // M-tile == XCD id
    int i  = bx >> 3;
    int tn = i % NTN;
    int b  = i / NTN;

    const unsigned short* Ab = A  + b * strideA + (size_t)tm * 256 * LDA;
    const unsigned short* Bb = Bm + b * strideB + (size_t)tn * 256 * LDB;

    int tid  = threadIdx.x;
    int w    = tid >> 6;
    int lane = tid & 63;
    int lrow = lane & 15;
    int lk4  = lane >> 4;
    int wm   = w >> 2;          // 0..1
    int wn   = w & 3;           // 0..3

    int bmax = BCOLS - tn * 256; if (bmax > 256) bmax = 256;

    if constexpr (EPI) {
        snm[tid] = (tid < 256) ? qq[b * LQ + tm * 256 + tid]
                               : kkn[b * LK + tn * 256 + (tid - 256)];
    }
    // Keep snm global loads ordered BEFORE staging so vmcnt issue-order
    // counting below stays exact.
    asm volatile("" ::: "memory");

    // One staging chunk: one global_load_lds per thread. LDS dest linear
    // (elem = s*4096 + tid*8 == kh*8192 + row*32 + ch*8); global source
    // column pre-swizzled. Global row clamped to rmax-1 (PV padding).
    auto stage_chunk = [&](const unsigned short* Gb, int ldg, int rmax,
                           unsigned short* Lb, int kt, int s) {
        int row = ((s & 1) << 7) | (tid >> 2);
        int kh  = s >> 1;
        int ch  = tid & 3;
        int gr  = row < rmax ? row : rmax - 1;
        int sc  = kt * 64 + kh * 32 + ((ch ^ ((row >> 1) & 3)) << 3);
        __builtin_amdgcn_global_load_lds(
            (const __attribute__((address_space(1))) void*)(Gb + (size_t)gr * ldg + sc),
            (__attribute__((address_space(3))) void*)(Lb + s * 4096 + w * 512),
            16, 0, 0);
    };

    // Prologue: tiles 0 (buf0) and 1 (buf1), 16 loads/thread in issue order.
    #pragma unroll
    for (int s = 0; s < 4; ++s) stage_chunk(Ab, LDA, 256,  lA,         0, s);
    #pragma unroll
    for (int s = 0; s < 4; ++s) stage_chunk(Bb, LDB, bmax, lB,         0, s);
    #pragma unroll
    for (int s = 0; s < 4; ++s) stage_chunk(Ab, LDA, 256,  lA + 16384, 1, s);
    #pragma unroll
    for (int s = 0; s < 4; ++s) stage_chunk(Bb, LDB, bmax, lB + 16384, 1, s);

    f32x4 acc[8][4] = {};

    auto bar = [&]() {
        __builtin_amdgcn_sched_barrier(0);
        asm volatile("" ::: "memory");
        __builtin_amdgcn_s_barrier();
        asm volatile("" ::: "memory");
        __builtin_amdgcn_sched_barrier(0);
    };

    auto run_iter = [&](int t, bool st) {
        int p = t & 1;
        const unsigned short* pA = lA + p * 16384;
        const unsigned short* pB = lB + p * 16384;
        unsigned short* sA = lA + p * 16384;
        unsigned short* sB = lB + p * 16384;
        int t2 = t + 2;
        s16x8 bf[4][2];
        #pragma unroll
        for (int j = 0; j < 4; ++j) {
            if (j == 0) {
                #pragma unroll
                for (int n = 0; n < 4; ++n)
                    #pragma unroll
                    for (int kh = 0; kh < 2; ++kh) {
                        int br = wn * 64 + n * 16 + lrow;
                        bf[n][kh] = *(const s16x8*)(pB + kh * 8192 + br * 32 +
                                                    ((lk4 ^ ((br >> 1) & 3)) << 3));
                    }
            }
            s16x8 af[2][2];
            #pragma unroll
            for (int m = 0; m < 2; ++m)
                #pragma unroll
                for (int kh = 0; kh < 2; ++kh) {
                    int ar = wm * 128 + (j * 2 + m) * 16 + lrow;
                    af[m][kh] = *(const s16x8*)(pA + kh * 8192 + ar * 32 +
                                                ((lk4 ^ ((ar >> 1) & 3)) << 3));
                }
            if (st) {
                if (j == 1) { stage_chunk(Bb, LDB, bmax, sB, t2, 0);
                              stage_chunk(Bb, LDB, bmax, sB, t2, 1); }
                if (j == 2) { stage_chunk(Bb, LDB, bmax, sB, t2, 2);
                              stage_chunk(Bb, LDB, bmax, sB, t2, 3); }
            }
            bar();
            __builtin_amdgcn_s_setprio(1);
            #pragma unroll
            for (int kh = 0; kh < 2; ++kh)
                #pragma unroll
                for (int m = 0; m < 2; ++m)
                    #pragma unroll
                    for (int n = 0; n < 4; ++n)
                        acc[j * 2 + m][n] = __builtin_amdgcn_mfma_f32_16x16x32_bf16(
                            af[m][kh], bf[n][kh], acc[j * 2 + m][n], 0, 0, 0);
            __builtin_amdgcn_s_setprio(0);
            bar();
        }
        if (st) {
            #pragma unroll
            for (int s = 0; s < 4; ++s) stage_chunk(Ab, LDA, 256, sA, t2, s);
        }
    };

    for (int t = 0; t < KT - 1; ++t) {
        // Tile t fully landed when <=8 outstanding (tile t+1's loads).
        asm volatile("s_waitcnt vmcnt(8)" ::: "memory");
        bar();
        run_iter(t, t + 2 < KT);
    }
    asm volatile("s_waitcnt vmcnt(0)" ::: "memory");
    bar();
    run_iter(KT - 1, false);

    // Epilogue. C/D layout (m89): col = lane&15, row = (lane>>4)*4 + rr.
    float* Cb = C + b * strideC + (size_t)(tm * 256) * ldc + tn * 256;
    #pragma unroll
    for (int mi = 0; mi < 8; ++mi) {
        int rb = wm * 128 + mi * 16 + lk4 * 4;
        #pragma unroll
        for (int ni = 0; ni < 4; ++ni) {
            int col = wn * 64 + ni * 16 + lrow;
            if (col < bmax) {
                #pragma unroll
                for (int rr = 0; rr < 4; ++rr) {
                    float val = acc[mi][ni][rr];
                    if constexpr (EPI)
                        val = (2.0f * val - snm[rb + rr] - snm[256 + col]) * (1.0f / 13.0f);
                    Cb[(size_t)(rb + rr) * ldc + col] = val;
                }
            }
        }
    }
}

// ---------------------------------------------------------------------------
// K2: per-row softmax fixup. One block per (b, q-row); 2048 logits live in
// registers (8/thread). Writes attn fp32, attn bf16 (ws), log_attn (in-place).
__global__ __launch_bounds__(256) void softmax_fix(float* __restrict__ logits,
                                                   float* __restrict__ attn,
                                                   unsigned short* __restrict__ a16) {
    __shared__ float redm[4], reds[4];
    size_t row = blockIdx.x;
    float* Lr = logits + row * LK;
    int tid = threadIdx.x;
    float x[8];
    *(float4*)(x)     = *(const float4*)(Lr + tid * 8);
    *(float4*)(x + 4) = *(const float4*)(Lr + tid * 8 + 4);

    float m = x[0];
    #pragma unroll
    for (int i = 1; i < 8; ++i) m = fmaxf(m, x[i]);
    #pragma unroll
    for (int o = 32; o; o >>= 1) m = fmaxf(m, __shfl_xor(m, o));
    int wv = tid >> 6, ln = tid & 63;
    if (ln == 0) redm[wv] = m;
    __syncthreads();
    m = fmaxf(fmaxf(redm[0], redm[1]), fmaxf(redm[2], redm[3]));

    float e[8];
    float s = 0.f;
    #pragma unroll
    for (int i = 0; i < 8; ++i) { e[i] = __expf(x[i] - m); s += e[i]; }
    #pragma unroll
    for (int o = 32; o; o >>= 1) s += __shfl_xor(s, o);
    if (ln == 0) reds[wv] = s;
    __syncthreads();
    s = reds[0] + reds[1] + reds[2] + reds[3];

    float lse = __logf(s);
    float inv = 1.0f / s;
    float at[8], la[8];
    #pragma unroll
    for (int i = 0; i < 8; ++i) { at[i] = e[i] * inv; la[i] = x[i] - m - lse; }

    float* Ar = attn + row * LK;
    *(float4*)(Ar + tid * 8)     = *(float4*)at;
    *(float4*)(Ar + tid * 8 + 4) = *(float4*)(at + 4);
    *(float4*)(Lr + tid * 8)     = *(float4*)la;
    *(float4*)(Lr + tid * 8 + 4) = *(float4*)(la + 4);

    unsigned short h[8];
    #pragma unroll
    for (int i = 0; i < 8; ++i) h[i] = f2bf(at[i]);
    unsigned short* Hr = a16 + row * LK;
    *(ushort4*)(Hr + tid * 8)     = *(ushort4*)h;
    *(ushort4*)(Hr + tid * 8 + 4) = *(ushort4*)(h + 4);
}

// ---------------------------------------------------------------------------
extern "C" void kernel_launch(void* const* d_in, const int* in_sizes, int n_in,
                              void* d_out, int out_size, void* d_ws, size_t ws_size,
                              hipStream_t stream) {
    const float* q = (const float*)d_in[0];
    const float* k = (const float*)d_in[1];
    const float* v = (const float*)d_in[2];

    float* out   = (float*)d_out;                      // (8, 2048, 640)
    float* attn  = out + (size_t)B_ * LQ * DD;         // (8, 2048, 2048)
    float* logat = attn + (size_t)B_ * LQ * LK;        // (8, 2048, 2048)

    // ws layout (needs ~130.2 MB, unchanged):
    unsigned short* q16  = (unsigned short*)d_ws;                 // 10485760 bf16
    unsigned short* k16  = q16 + (size_t)B_ * LQ * DD;            // 10485760
    unsigned short* v16t = k16 + (size_t)B_ * LK * DD;            // 10485760 (B, D, LK)
    unsigned short* a16  = v16t + (size_t)B_ * DD * LK;           // 33554432 (B, LQ, LK)
    float* qq  = (float*)(a16 + (size_t)B_ * LQ * LK);            // 16384
    float* kkn = qq + (size_t)B_ * LQ;                            // 16384

    cvt_norm2<<<2 * B_ * LQ / 4, 256, 0, stream>>>(q, k, q16, k16, qq, kkn);
    cvt_transpose_v<<<B_ * (LK / 64) * (DD / 64), 256, 0, stream>>>(v, v16t);

    // QK^T -> raw logits into log_attn region. 256x256 tiles: grid = 8*8*8.
    gemm8p<DD, DD, DD, 8, LK, true><<<B_ * 8 * 8, 512, 0, stream>>>(
        q16, k16, logat,
        (size_t)LQ * DD, (size_t)LK * DD, (size_t)LQ * LK, LK, qq, kkn);

    // softmax fixup: one block per row.
    softmax_fix<<<B_ * LQ, 256, 0, stream>>>(logat, attn, a16);

    // PV: attn_bf16 (2048x2048) @ v^T_bf16 (640x2048) -> out.
    // 256x256 tiles (N clamped at 640): grid = 8*3*8 = 192 -> single round.
    gemm8p<LK, LK, LK, 3, DD, false><<<B_ * 3 * 8, 512, 0, stream>>>(
        a16, v16t, out,
        (size_t)LQ * LK, (size_t)DD * LK, (size_t)LQ * DD, DD, nullptr, nullptr);
}

// Round 3
// 595.887 us; speedup vs baseline: 1.0511x; 1.0254x over previous
//
#include <hip/hip_runtime.h>

// Problem: B=8, Lq=Lk=2048, D=640, fp32.
//   logits = (2*q.k - ||q||^2 - ||k||^2) / 13
//   log_attn = log_softmax(logits); attn = exp(log_attn); out = attn @ v
// Outputs concatenated in d_out: out (8*2048*640) | attn (8*2048*2048) | log_attn (8*2048*2048)

#define B_   8
#define LQ   2048
#define LK   2048
#define DD   640

typedef short s16x8 __attribute__((ext_vector_type(8)));
typedef float f32x4 __attribute__((ext_vector_type(4)));

__device__ __forceinline__ unsigned short f2bf(float x) {
    unsigned int u = __float_as_uint(x);
    unsigned int r = (u + 0x7fffu + ((u >> 16) & 1u)) >> 16;
    return (unsigned short)r;
}

// ---------------------------------------------------------------------------
// K0: merged pre-pass. Blocks [0, 8192): fp32->bf16 convert + row ||.||^2 for
// q and k (one wave per row). Blocks [8192, 10752): v (B,2048,640) fp32 ->
// v^T (B,640,2048) bf16 via 64x64 LDS tiles.
__global__ __launch_bounds__(256) void cvt_all(const float* __restrict__ q,
                                               const float* __restrict__ k,
                                               const float* __restrict__ v,
                                               unsigned short* __restrict__ q16,
                                               unsigned short* __restrict__ k16,
                                               unsigned short* __restrict__ vt,
                                               float* __restrict__ qq,
                                               float* __restrict__ kkn) {
    __shared__ float tile[64][65];
    int bx = blockIdx.x;
    if (bx < 8192) {
        int row  = bx * 4 + (threadIdx.x >> 6);
        int lane = threadIdx.x & 63;
        const float* src;
        unsigned short* dst;
        float* nrm;
        int r;
        if (row < B_ * LQ) { src = q; dst = q16; nrm = qq;  r = row; }
        else               { src = k; dst = k16; nrm = kkn; r = row - B_ * LQ; }
        const float4* s = (const float4*)(src + (size_t)r * DD);
        unsigned short* d = dst + (size_t)r * DD;
        float ss = 0.f;
        for (int t = lane; t < DD / 4; t += 64) {
            float4 x = s[t];
            ss += x.x * x.x + x.y * x.y + x.z * x.z + x.w * x.w;
            ushort4 o;
            o.x = f2bf(x.x); o.y = f2bf(x.y); o.z = f2bf(x.z); o.w = f2bf(x.w);
            *(ushort4*)(d + t * 4) = o;
        }
        #pragma unroll
        for (int o = 32; o; o >>= 1) ss += __shfl_xor(ss, o);
        if (lane == 0) nrm[r] = ss;
    } else {
        int r0 = bx - 8192;
        int b  = r0 / 320;
        int r  = r0 % 320;
        int tj = r / 10;   // j-tile (0..31)
        int td = r % 10;   // d-tile (0..9)
        const float* src = v + (size_t)b * LK * DD + (size_t)tj * 64 * DD + td * 64;
        for (int e = threadIdx.x; e < 4096; e += 256) {
            int rr = e >> 6, cc = e & 63;
            tile[rr][cc] = src[(size_t)rr * DD + cc];
        }
        __syncthreads();
        unsigned short* dst = vt + (size_t)b * DD * LK + (size_t)td * 64 * LK + tj * 64;
        for (int e = threadIdx.x; e < 4096; e += 256) {
            int rr = e >> 6, cc = e & 63;  // rr = local d, cc = local j
            dst[(size_t)rr * LK + cc] = f2bf(tile[cc][rr]);
        }
    }
}

// ---------------------------------------------------------------------------
// QK^T NT-GEMM, 8-wave 256x256 tile, 4-phase-per-K-tile counted-vmcnt schedule
// (UNCHANGED from round 2 -- control). See round-2 comments for the full
// schedule derivation. EPI: val = (2*acc - qq[row] - kk[col]) / 13.
template <int LDA, int LDB, int KSZ, int NTN, int BCOLS, bool EPI>
__global__ __launch_bounds__(512, 2) void gemm8p(
    const unsigned short* __restrict__ A, const unsigned short* __restrict__ Bm,
    float* __restrict__ C, size_t strideA, size_t strideB, size_t strideC, int ldc,
    const float* __restrict__ qq, const float* __restrict__ kkn) {

    constexpr int KT = KSZ / 64;

    __shared__ unsigned short lA[2 * 16384];
    __shared__ unsigned short lB[2 * 16384];
    __shared__ float snm[512];

    int bx = blockIdx.x;
    int tm = bx & 7;            // M-tile == XCD id
    int i  = bx >> 3;
    int tn = i % NTN;
    int b  = i / NTN;

    const unsigned short* Ab = A  + b * strideA + (size_t)tm * 256 * LDA;
    const unsigned short* Bb = Bm + b * strideB + (size_t)tn * 256 * LDB;

    int tid  = threadIdx.x;
    int w    = tid >> 6;
    int lane = tid & 63;
    int lrow = lane & 15;
    int lk4  = lane >> 4;
    int wm   = w >> 2;          // 0..1
    int wn   = w & 3;           // 0..3

    int bmax = BCOLS - tn * 256; if (bmax > 256) bmax = 256;

    if constexpr (EPI) {
        snm[tid] = (tid < 256) ? qq[b * LQ + tm * 256 + tid]
                               : kkn[b * LK + tn * 256 + (tid - 256)];
    }
    asm volatile("" ::: "memory");

    auto stage_chunk = [&](const unsigned short* Gb, int ldg, int rmax,
                           unsigned short* Lb, int kt, int s) {
        int row = ((s & 1) << 7) | (tid >> 2);
        int kh  = s >> 1;
        int ch  = tid & 3;
        int gr  = row < rmax ? row : rmax - 1;
        int sc  = kt * 64 + kh * 32 + ((ch ^ ((row >> 1) & 3)) << 3);
        __builtin_amdgcn_global_load_lds(
            (const __attribute__((address_space(1))) void*)(Gb + (size_t)gr * ldg + sc),
            (__attribute__((address_space(3))) void*)(Lb + s * 4096 + w * 512),
            16, 0, 0);
    };

    #pragma unroll
    for (int s = 0; s < 4; ++s) stage_chunk(Ab, LDA, 256,  lA,         0, s);
    #pragma unroll
    for (int s = 0; s < 4; ++s) stage_chunk(Bb, LDB, bmax, lB,         0, s);
    #pragma unroll
    for (int s = 0; s < 4; ++s) stage_chunk(Ab, LDA, 256,  lA + 16384, 1, s);
    #pragma unroll
    for (int s = 0; s < 4; ++s) stage_chunk(Bb, LDB, bmax, lB + 16384, 1, s);

    f32x4 acc[8][4] = {};

    auto bar = [&]() {
        __builtin_amdgcn_sched_barrier(0);
        asm volatile("" ::: "memory");
        __builtin_amdgcn_s_barrier();
        asm volatile("" ::: "memory");
        __builtin_amdgcn_sched_barrier(0);
    };

    auto run_iter = [&](int t, bool st) {
        int p = t & 1;
        const unsigned short* pA = lA + p * 16384;
        const unsigned short* pB = lB + p * 16384;
        unsigned short* sA = lA + p * 16384;
        unsigned short* sB = lB + p * 16384;
        int t2 = t + 2;
        s16x8 bf[4][2];
        #pragma unroll
        for (int j = 0; j < 4; ++j) {
            if (j == 0) {
                #pragma unroll
                for (int n = 0; n < 4; ++n)
                    #pragma unroll
                    for (int kh = 0; kh < 2; ++kh) {
                        int br = wn * 64 + n * 16 + lrow;
                        bf[n][kh] = *(const s16x8*)(pB + kh * 8192 + br * 32 +
                                                    ((lk4 ^ ((br >> 1) & 3)) << 3));
                    }
            }
            s16x8 af[2][2];
            #pragma unroll
            for (int m = 0; m < 2; ++m)
                #pragma unroll
                for (int kh = 0; kh < 2; ++kh) {
                    int ar = wm * 128 + (j * 2 + m) * 16 + lrow;
                    af[m][kh] = *(const s16x8*)(pA + kh * 8192 + ar * 32 +
                                                ((lk4 ^ ((ar >> 1) & 3)) << 3));
                }
            if (st) {
                if (j == 1) { stage_chunk(Bb, LDB, bmax, sB, t2, 0);
                              stage_chunk(Bb, LDB, bmax, sB, t2, 1); }
                if (j == 2) { stage_chunk(Bb, LDB, bmax, sB, t2, 2);
                              stage_chunk(Bb, LDB, bmax, sB, t2, 3); }
            }
            bar();
            __builtin_amdgcn_s_setprio(1);
            #pragma unroll
            for (int kh = 0; kh < 2; ++kh)
                #pragma unroll
                for (int m = 0; m < 2; ++m)
                    #pragma unroll
                    for (int n = 0; n < 4; ++n)
                        acc[j * 2 + m][n] = __builtin_amdgcn_mfma_f32_16x16x32_bf16(
                            af[m][kh], bf[n][kh], acc[j * 2 + m][n], 0, 0, 0);
            __builtin_amdgcn_s_setprio(0);
            bar();
        }
        if (st) {
            #pragma unroll
            for (int s = 0; s < 4; ++s) stage_chunk(Ab, LDA, 256, sA, t2, s);
        }
    };

    for (int t = 0; t < KT - 1; ++t) {
        asm volatile("s_waitcnt vmcnt(8)" ::: "memory");
        bar();
        run_iter(t, t + 2 < KT);
    }
    asm volatile("s_waitcnt vmcnt(0)" ::: "memory");
    bar();
    run_iter(KT - 1, false);

    float* Cb = C + b * strideC + (size_t)(tm * 256) * ldc + tn * 256;
    #pragma unroll
    for (int mi = 0; mi < 8; ++mi) {
        int rb = wm * 128 + mi * 16 + lk4 * 4;
        #pragma unroll
        for (int ni = 0; ni < 4; ++ni) {
            int col = wn * 64 + ni * 16 + lrow;
            if (col < bmax) {
                #pragma unroll
                for (int rr = 0; rr < 4; ++rr) {
                    float val = acc[mi][ni][rr];
                    if constexpr (EPI)
                        val = (2.0f * val - snm[rb + rr] - snm[256 + col]) * (1.0f / 13.0f);
                    Cb[(size_t)(rb + rr) * ldc + col] = val;
                }
            }
        }
    }
}

// ---------------------------------------------------------------------------
// PV NT-GEMM: out[i][d] = sum_k attn16[i][k] * v16t[d][k]. BM=256, BN=160
// (640 = 4x160 exact), BK=64, 512 threads = 8 waves (4M x 2N), wave tile
// 64x80 (acc[4][5] f32x4 = 80 VGPR). Same 4-phase counted-vmcnt schedule as
// gemm8p. grid = 8b * 8tm * 4tn = 256 blocks = EXACTLY one full round at
// 1 block/CU (round-2's 192-block grid idled 25% of the chip).
// XCD map: bx = (b*4+tn)*8 + ((b+tm)&7) -> the 4 tn-blocks sharing an A strip
// (1 MB of a16) colocate on one XCD (L2-shared); v16t strips cross-XCD via L3.
// B staging: 160 rows padded to 192 (3 exact 8KB chunks/thread; case split at
// tid=256 = wave boundary -> wave-uniform global_load_lds; dummy rows clamp to
// row 159 and are never read). Per-tile loads/thread = A4 + B3 = 7 ->
// steady-state wait = vmcnt(7).
__global__ __launch_bounds__(512, 2) void gemm_pv(
    const unsigned short* __restrict__ A, const unsigned short* __restrict__ Bm,
    float* __restrict__ C) {

    constexpr int KT = LK / 64;          // 32

    __shared__ unsigned short lA[2 * 16384];   // 64 KB: [kh][row 256][32]
    __shared__ unsigned short lB[2 * 12288];   // 48 KB: [kh][row 192][32]

    int bx = blockIdx.x;
    int x  = bx & 7;
    int r  = bx >> 3;        // = b*4 + tn
    int b  = r >> 2;
    int tn = r & 3;
    int tm = (x - b) & 7;

    const unsigned short* Ab = A  + (size_t)b * LQ * LK + (size_t)tm * 256 * LK;
    const unsigned short* Bb = Bm + (size_t)b * DD * LK + (size_t)tn * 160 * LK;

    int tid  = threadIdx.x;
    int w    = tid >> 6;
    int lane = tid & 63;
    int lrow = lane & 15;
    int lk4  = lane >> 4;
    int wm   = w >> 1;          // 0..3
    int wn   = w & 1;           // 0..1

    auto stageA = [&](int kt, int p, int s) {
        int row = ((s & 1) << 7) | (tid >> 2);
        int kh  = s >> 1;
        int ch  = tid & 3;
        int sc  = kt * 64 + kh * 32 + ((ch ^ ((row >> 1) & 3)) << 3);
        __builtin_amdgcn_global_load_lds(
            (const __attribute__((address_space(1))) void*)(Ab + (size_t)row * LK + sc),
            (__attribute__((address_space(3))) void*)(lA + p * 16384 + s * 4096 + w * 512),
            16, 0, 0);
    };
    auto stageB = [&](int kt, int p, int s) {
        int g   = s * 512 + tid;           // 0..1535 over 3 chunks
        int kh  = g >= 768;
        int rem = g - kh * 768;
        int row = rem >> 2;                 // 0..191 (>=160 are dummies)
        int ch  = rem & 3;
        int gr  = row < 160 ? row : 159;
        int sc  = kt * 64 + kh * 32 + ((ch ^ ((row >> 1) & 3)) << 3);
        __builtin_amdgcn_global_load_lds(
            (const __attribute__((address_space(1))) void*)(Bb + (size_t)gr * LK + sc),
            (__attribute__((address_space(3))) void*)(lB + p * 12288 + s * 4096 + w * 512),
            16, 0, 0);
    };

    // Prologue: tiles 0 and 1 (7 loads/thread each, issue order A then B).
    #pragma unroll
    for (int s = 0; s < 4; ++s) stageA(0, 0, s);
    #pragma unroll
    for (int s = 0; s < 3; ++s) stageB(0, 0, s);
    #pragma unroll
    for (int s = 0; s < 4; ++s) stageA(1, 1, s);
    #pragma unroll
    for (int s = 0; s < 3; ++s) stageB(1, 1, s);

    f32x4 acc[4][5] = {};

    auto bar = [&]() {
        __builtin_amdgcn_sched_barrier(0);
        asm volatile("" ::: "memory");
        __builtin_amdgcn_s_barrier();
        asm volatile("" ::: "memory");
        __builtin_amdgcn_sched_barrier(0);
    };

    auto run_iter = [&](int t, bool st) {
        int p = t & 1;
        const unsigned short* pA = lA + p * 16384;
        const unsigned short* pB = lB + p * 12288;
        int t2 = t + 2;
        s16x8 bf[5][2];
        #pragma unroll
        for (int j = 0; j < 4; ++j) {
            if (j == 0) {
                #pragma unroll
                for (int n = 0; n < 5; ++n)
                    #pragma unroll
                    for (int kh = 0; kh < 2; ++kh) {
                        int br = wn * 80 + n * 16 + lrow;
                        bf[n][kh] = *(const s16x8*)(pB + kh * 6144 + br * 32 +
                                                    ((lk4 ^ ((br >> 1) & 3)) << 3));
                    }
            }
            s16x8 af[2];
            #pragma unroll
            for (int kh = 0; kh < 2; ++kh) {
                int ar = wm * 64 + j * 16 + lrow;
                af[kh] = *(const s16x8*)(pA + kh * 8192 + ar * 32 +
                                         ((lk4 ^ ((ar >> 1) & 3)) << 3));
            }
            if (st) {
                if (j == 1) { stageB(t2, p, 0); stageB(t2, p, 1); }
                if (j == 2) { stageB(t2, p, 2); }
            }
            bar();
            __builtin_amdgcn_s_setprio(1);
            #pragma unroll
            for (int kh = 0; kh < 2; ++kh)
                #pragma unroll
                for (int n = 0; n < 5; ++n)
                    acc[j][n] = __builtin_amdgcn_mfma_f32_16x16x32_bf16(
                        af[kh], bf[n][kh], acc[j][n], 0, 0, 0);
            __builtin_amdgcn_s_setprio(0);
            bar();
        }
        if (st) {
            #pragma unroll
            for (int s = 0; s < 4; ++s) stageA(t2, p, s);
        }
    };

    for (int t = 0; t < KT - 1; ++t) {
        // Tile t fully landed when <=7 outstanding (tile t+1's loads).
        asm volatile("s_waitcnt vmcnt(7)" ::: "memory");
        bar();
        run_iter(t, t + 2 < KT);
    }
    asm volatile("s_waitcnt vmcnt(0)" ::: "memory");
    bar();
    run_iter(KT - 1, false);

    // Epilogue. C/D layout: col = lane&15, row = (lane>>4)*4 + rr.
    float* Cb = C + (size_t)b * LQ * DD + (size_t)(tm * 256) * DD + tn * 160;
    #pragma unroll
    for (int mi = 0; mi < 4; ++mi) {
        int rb = wm * 64 + mi * 16 + lk4 * 4;
        #pragma unroll
        for (int ni = 0; ni < 5; ++ni) {
            int col = wn * 80 + ni * 16 + lrow;
            #pragma unroll
            for (int rr = 0; rr < 4; ++rr)
                Cb[(size_t)(rb + rr) * DD + col] = acc[mi][ni][rr];
        }
    }
}

// ---------------------------------------------------------------------------
// K2: per-row softmax fixup. One block per (b, q-row); 2048 logits live in
// registers (8/thread). Writes attn fp32, attn bf16 (ws), log_attn (in-place).
__global__ __launch_bounds__(256) void softmax_fix(float* __restrict__ logits,
                                                   float* __restrict__ attn,
                                                   unsigned short* __restrict__ a16) {
    __shared__ float redm[4], reds[4];
    size_t row = blockIdx.x;
    float* Lr = logits + row * LK;
    int tid = threadIdx.x;
    float x[8];
    *(float4*)(x)     = *(const float4*)(Lr + tid * 8);
    *(float4*)(x + 4) = *(const float4*)(Lr + tid * 8 + 4);

    float m = x[0];
    #pragma unroll
    for (int i = 1; i < 8; ++i) m = fmaxf(m, x[i]);
    #pragma unroll
    for (int o = 32; o; o >>= 1) m = fmaxf(m, __shfl_xor(m, o));
    int wv = tid >> 6, ln = tid & 63;
    if (ln == 0) redm[wv] = m;
    __syncthreads();
    m = fmaxf(fmaxf(redm[0], redm[1]), fmaxf(redm[2], redm[3]));

    float e[8];
    float s = 0.f;
    #pragma unroll
    for (int i = 0; i < 8; ++i) { e[i] = __expf(x[i] - m); s += e[i]; }
    #pragma unroll
    for (int o = 32; o; o >>= 1) s += __shfl_xor(s, o);
    if (ln == 0) reds[wv] = s;
    __syncthreads();
    s = reds[0] + reds[1] + reds[2] + reds[3];

    float lse = __logf(s);
    float inv = 1.0f / s;
    float at[8], la[8];
    #pragma unroll
    for (int i = 0; i < 8; ++i) { at[i] = e[i] * inv; la[i] = x[i] - m - lse; }

    float* Ar = attn + row * LK;
    *(float4*)(Ar + tid * 8)     = *(float4*)at;
    *(float4*)(Ar + tid * 8 + 4) = *(float4*)(at + 4);
    *(float4*)(Lr + tid * 8)     = *(float4*)la;
    *(float4*)(Lr + tid * 8 + 4) = *(float4*)(la + 4);

    unsigned short h[8];
    #pragma unroll
    for (int i = 0; i < 8; ++i) h[i] = f2bf(at[i]);
    unsigned short* Hr = a16 + row * LK;
    *(ushort4*)(Hr + tid * 8)     = *(ushort4*)h;
    *(ushort4*)(Hr + tid * 8 + 4) = *(ushort4*)(h + 4);
}

// ---------------------------------------------------------------------------
extern "C" void kernel_launch(void* const* d_in, const int* in_sizes, int n_in,
                              void* d_out, int out_size, void* d_ws, size_t ws_size,
                              hipStream_t stream) {
    const float* q = (const float*)d_in[0];
    const float* k = (const float*)d_in[1];
    const float* v = (const float*)d_in[2];

    float* out   = (float*)d_out;                      // (8, 2048, 640)
    float* attn  = out + (size_t)B_ * LQ * DD;         // (8, 2048, 2048)
    float* logat = attn + (size_t)B_ * LQ * LK;        // (8, 2048, 2048)

    // ws layout (needs ~130.2 MB, unchanged):
    unsigned short* q16  = (unsigned short*)d_ws;                 // 10485760 bf16
    unsigned short* k16  = q16 + (size_t)B_ * LQ * DD;            // 10485760
    unsigned short* v16t = k16 + (size_t)B_ * LK * DD;            // 10485760 (B, D, LK)
    unsigned short* a16  = v16t + (size_t)B_ * DD * LK;           // 33554432 (B, LQ, LK)
    float* qq  = (float*)(a16 + (size_t)B_ * LQ * LK);            // 16384
    float* kkn = qq + (size_t)B_ * LQ;                            // 16384

    // Merged pre-pass: norms+cvt (blocks 0..8191) and v-transpose (8192..10751).
    cvt_all<<<8192 + B_ * (LK / 64) * (DD / 64), 256, 0, stream>>>(
        q, k, v, q16, k16, v16t, qq, kkn);

    // QK^T -> raw logits into log_attn region. 256x256 tiles: grid = 8*8*8.
    gemm8p<DD, DD, DD, 8, LK, true><<<B_ * 8 * 8, 512, 0, stream>>>(
        q16, k16, logat,
        (size_t)LQ * DD, (size_t)LK * DD, (size_t)LQ * LK, LK, qq, kkn);

    // softmax fixup: one block per row.
    softmax_fix<<<B_ * LQ, 256, 0, stream>>>(logat, attn, a16);

    // PV: attn_bf16 (2048x2048) @ v^T_bf16 (640x2048) -> out.
    // 256x160 tiles: grid = 8*8*4 = 256 = exactly one full round.
    gemm_pv<<<B_ * 8 * 4, 512, 0, stream>>>(a16, v16t, out);
}